// Round 9
// baseline (165.517 us; speedup 1.0000x reference)
//
#include <hip/hip_runtime.h>
#include <math.h>

#define N_S 32
#define C_DIM 3
#define F_DIM 3277
#define T_DIM 256
#define FT (F_DIM * T_DIM)          /* 838912  */
#define CFT (F_DIM * T_DIM * C_DIM) /* 2516736 */
#define CFT4 (CFT / 4)              /* 629184 float4 per sample */
#define FC_IDX 1084
#define N_NOISE 2949
#define NB 64                       /* blocks per sample */
#define NPART NB
#define STRIDE4 (NB * 256)          /* 16384 float4 grid-stride within sample */
/* 629184 = 38*16384 + 6592 -> iterations 0..37 unconditional, 38 partial */

typedef float f4 __attribute__((ext_vector_type(4)));

struct WS {
  float              tot_p[N_S][NB];   /* per-block |x| sum, whole sample   */
  float              in_p[N_S][NB];    /* per-block |x| sum, in-band rows   */
  int                mid[N_S];
  int                hb[N_S];
  unsigned long long tbits[N_S][4];
};

// ---- K1: copy-clone — NT load x[i], accumulate, NT store 0 -> out[i] --------
// Block (b,n) strides sample n's float4 space at STRIDE4. Per wave-iteration
// the 64 lanes cover one full T-row (wave-uniform row r), so the in-band test
// is one unsigned compare -> m in {0,1}; excluded sum via fma.
__global__ __launch_bounds__(256) void k_main(const f4* __restrict__ xv,
                                              f4* __restrict__ ov,
                                              WS* __restrict__ ws) {
  int n = blockIdx.y;
  int b = blockIdx.x;
  int t = threadIdx.x;
  const f4* smp  = xv + (size_t)n * CFT4;
  f4*       osmp = ov + (size_t)n * CFT4;
  int i0 = b * 256 + t;
  int r  = i0 >> 6;                 /* row within plane, < 3277; wraps below */
  const f4 z = {0.f, 0.f, 0.f, 0.f};
  float t0 = 0.f, t1 = 0.f, t2 = 0.f, t3 = 0.f;  /* total accumulators   */
  float e0 = 0.f, e1 = 0.f, e2 = 0.f, e3 = 0.f;  /* in-band (excluded)   */

#define STEP(J, TACC, EACC)                                                    \
  {                                                                            \
    int i = i0 + (it + (J)) * STRIDE4;                                         \
    if ((it + (J)) < 38 || i < CFT4) {                                         \
      f4 v = __builtin_nontemporal_load(smp + i);                              \
      float m = ((unsigned)(r - 1638) < 328u) ? 1.f : 0.f;                     \
      TACC += fabsf(v.x) + fabsf(v.y) + fabsf(v.z) + fabsf(v.w);               \
      EACC = fmaf(m, fabsf(v.x), EACC);                                        \
      EACC = fmaf(m, fabsf(v.y), EACC);                                        \
      EACC = fmaf(m, fabsf(v.z), EACC);                                        \
      EACC = fmaf(m, fabsf(v.w), EACC);                                        \
      __builtin_nontemporal_store(z, osmp + i);                                \
    }                                                                          \
    r += 256; if (r >= F_DIM) r -= F_DIM;                                      \
  }

  #pragma unroll
  for (int it = 0; it < 40; it += 4) {
    if (it < 39) {
      STEP(0, t0, e0)
      if (it + 1 < 39) STEP(1, t1, e1)
      if (it + 2 < 39) STEP(2, t2, e2)
      if (it + 3 < 39) STEP(3, t3, e3)
    }
  }
#undef STEP

  float tt = (t0 + t1) + (t2 + t3);
  float ee = (e0 + e1) + (e2 + e3);
  for (int off = 32; off; off >>= 1) {
    tt += __shfl_down(tt, off);
    ee += __shfl_down(ee, off);
  }
  __shared__ double wsA[4], wsB[4];
  int w = t >> 6, lane = t & 63;
  if (lane == 0) { wsA[w] = (double)tt; wsB[w] = (double)ee; }
  __syncthreads();
  if (t == 0) {
    ws->tot_p[n][b] = (float)(wsA[0] + wsA[1] + wsA[2] + wsA[3]);
    ws->in_p[n][b]  = (float)(wsB[0] + wsB[1] + wsB[2] + wsB[3]);
  }
}

// ---- K2: per-sample stats — verbatim except noise = total - inband ----------
__global__ __launch_bounds__(256) void k_stats(const float* __restrict__ x,
                                               WS* __restrict__ ws) {
  int n = blockIdx.x;
  int t = threadIdx.x;
  const float* p = x + (size_t)n * CFT + (size_t)FC_IDX * T_DIM + t;
  float m = fabsf(p[0]) + fabsf(p[FT]) + fabsf(p[2 * FT]);

  __shared__ float  smag[256];
  __shared__ float  sv[256];
  __shared__ int    si[256];
  __shared__ double sd[256];
  smag[t] = m; sv[t] = m; si[t] = t;
  sd[t] = (t < NPART) ? ((double)ws->tot_p[n][t] - (double)ws->in_p[n][t]) : 0.0;
  __syncthreads();
  for (int s = 128; s > 0; s >>= 1) {
    if (t < s) {
      if (sv[t + s] > sv[t] || (sv[t + s] == sv[t] && si[t + s] < si[t])) {
        sv[t] = sv[t + s]; si[t] = si[t + s];
      }
      sd[t] += sd[t + s];
    }
    __syncthreads();
  }
  if (t == 0) {
    int mid = si[0];
    double noise_d = sd[0] / ((double)N_NOISE * (double)T_DIM);
    int lo = mid - 8; if (lo < 0) lo = 0;
    int hi = mid + 8; if (hi > T_DIM) hi = T_DIM;
    double sig_d = 0.0;
    for (int tt = lo; tt < hi; ++tt) sig_d += (double)smag[tt];
    float sig = (float)sig_d, noise = (float)noise_d;
    float d   = sig - noise;
    float snr = 10.0f * log10f((d * d) / (noise * noise));
    float hbf = 12.5f * (snr - 20.0f) + 27.0f;
    int hb = (int)truncf(hbf);
    if (hb < 8) hb = 8;
    ws->mid[n] = mid;
    ws->hb[n]  = hb;
    int wlo = mid - 8, whi = mid + 8;
    #pragma unroll
    for (int wd = 0; wd < 4; ++wd) {
      int base = wd * 64;
      int a = wlo - base; if (a < 0) a = 0;
      int bq = whi - base; if (bq > 64) bq = 64;
      unsigned long long msk = 0ULL;
      if (bq > a) {
        unsigned long long hiM = (bq >= 64) ? ~0ULL : ((1ULL << bq) - 1ULL);
        unsigned long long loM = (1ULL << a) - 1ULL;
        msk = hiM & ~loM;
      }
      ws->tbits[n][wd] = msk;
    }
  }
}

// ---- K3: band rewrite — VERBATIM from rounds 2/3/6/8 (passed) ---------------
__global__ __launch_bounds__(256) void k_band(const float* __restrict__ x,
                                              float* __restrict__ out,
                                              const WS* __restrict__ ws) {
  __shared__ unsigned long long um[4];
  int f = blockIdx.x;
  int t = threadIdx.x;
  if (t < 4) {
    unsigned long long m = 0ULL;
    #pragma unroll 4
    for (int n = 0; n < N_S; ++n) {
      int hb = ws->hb[n];
      if (f >= FC_IDX - hb && f < FC_IDX + hb) m |= ws->tbits[n][t];
    }
    um[t] = m;
  }
  __syncthreads();
  if ((um[0] | um[1] | um[2] | um[3]) == 0ULL) return;  // row outside all bands

  bool keep = (um[t >> 6] >> (t & 63)) & 1ULL;
  const float* xr   = x   + (size_t)f * T_DIM + t;
  float*       orow = out + (size_t)f * T_DIM + t;
  #pragma unroll 4
  for (int nc = 0; nc < N_S * C_DIM; ++nc) {
    size_t off = (size_t)nc * FT;
    float v = keep ? xr[off] : 0.f;
    orow[off] = v;
  }
}

extern "C" void kernel_launch(void* const* d_in, const int* in_sizes, int n_in,
                              void* d_out, int out_size, void* d_ws, size_t ws_size,
                              hipStream_t stream) {
  const float* x   = (const float*)d_in[0];
  float*       out = (float*)d_out;
  WS*          ws  = (WS*)d_ws;

  dim3 gm(NB, N_S);
  k_main <<<gm, 256, 0, stream>>>((const f4*)x, (f4*)out, ws);
  k_stats<<<N_S, 256, 0, stream>>>(x, ws);
  k_band <<<F_DIM, 256, 0, stream>>>(x, out, ws);
}

// Round 10
// 130.232 us; speedup vs baseline: 1.2709x; 1.2709x over previous
//
#include <hip/hip_runtime.h>
#include <math.h>

#define N_S 32
#define C_DIM 3
#define F_DIM 3277
#define T_DIM 256
#define FT (F_DIM * T_DIM)          /* 838912  */
#define CFT (F_DIM * T_DIM * C_DIM) /* 2516736 */
#define CFT4 (CFT / 4)              /* 629184 float4 per sample */
#define FC_IDX 1084
#define N_NOISE 2949
#define NQ (3 * N_NOISE * 64)       /* 566208 noise float4s per sample */
#define TH0 104832                  /* 1638*64 */
#define TH1 293568                  /* TH0 + 188736 */
#define TH2 482304                  /* TH0 + 2*188736 */
#define SKIP4 20992                 /* 328*64 */
#define NB 64                       /* noise blocks per sample */
#define NPART NB
#define QPB (NQ / NB)               /* 8847 noise float4 per block (exact) */
#define TOTAL4 ((N_S * CFT) / 4)    /* 20,133,888 */

typedef float f4 __attribute__((ext_vector_type(4)));

struct WS {
  float              noise_partial[N_S][256];
  int                mid[N_S];
  int                hb[N_S];
  unsigned long long tbits[N_S][4];
  unsigned long long mask[F_DIM][4];
};

// ---- K1: noise partials — NT loads, per-block CONTIGUOUS linear walk --------
// Block (b,n) streams noise-index range [b*QPB, (b+1)*QPB) of sample n:
// a linear 141.5 KB region per block (single 328-row jump possible mid-range),
// vs R7's 4KB/256KB comb. Only variable changed this round.
__global__ __launch_bounds__(256) void k_noise(const f4* __restrict__ xv,
                                               WS* __restrict__ ws) {
  int n = blockIdx.y;
  int b = blockIdx.x;
  int t = threadIdx.x;
  const f4* smp = xv + (size_t)n * CFT4;
  int lo = b * QPB;
  int hi = lo + QPB;
  float a0 = 0.f, a1 = 0.f, a2 = 0.f, a3 = 0.f;

#define LOADACC(J, ACC)                                                        \
  {                                                                            \
    int q = j0 + (J) * 256 + t;                                                \
    if (q < hi) {                                                              \
      int add = (q >= TH0) * SKIP4 + (q >= TH1) * SKIP4 + (q >= TH2) * SKIP4;  \
      f4 v = __builtin_nontemporal_load(smp + q + add);                        \
      ACC += fabsf(v.x) + fabsf(v.y) + fabsf(v.z) + fabsf(v.w);                \
    }                                                                          \
  }

  for (int j0 = lo; j0 < hi; j0 += 1024) {
    LOADACC(0, a0)
    LOADACC(1, a1)
    LOADACC(2, a2)
    LOADACC(3, a3)
  }
#undef LOADACC

  float acc = (a0 + a1) + (a2 + a3);
  for (int off = 32; off; off >>= 1) acc += __shfl_down(acc, off);
  __shared__ double wsum[4];
  int w = t >> 6, lane = t & 63;
  if (lane == 0) wsum[w] = (double)acc;
  __syncthreads();
  if (t == 0) {
    ws->noise_partial[n][b] = (float)(wsum[0] + wsum[1] + wsum[2] + wsum[3]);
  }
}

// ---- K2: per-sample stats — VERBATIM from round 7 (passed, 131 µs best) -----
__global__ __launch_bounds__(256) void k_stats(const float* __restrict__ x,
                                               WS* __restrict__ ws) {
  int n = blockIdx.x;
  int t = threadIdx.x;
  const float* p = x + (size_t)n * CFT + (size_t)FC_IDX * T_DIM + t;
  float m = fabsf(p[0]) + fabsf(p[FT]) + fabsf(p[2 * FT]);

  __shared__ float  smag[256];
  __shared__ float  sv[256];
  __shared__ int    si[256];
  __shared__ double sd[256];
  smag[t] = m; sv[t] = m; si[t] = t;
  sd[t] = (t < NPART) ? (double)ws->noise_partial[n][t] : 0.0;
  __syncthreads();
  for (int s = 128; s > 0; s >>= 1) {
    if (t < s) {
      if (sv[t + s] > sv[t] || (sv[t + s] == sv[t] && si[t + s] < si[t])) {
        sv[t] = sv[t + s]; si[t] = si[t + s];
      }
      sd[t] += sd[t + s];
    }
    __syncthreads();
  }
  if (t == 0) {
    int mid = si[0];
    double noise_d = sd[0] / ((double)N_NOISE * (double)T_DIM);
    int lo = mid - 8; if (lo < 0) lo = 0;
    int hi = mid + 8; if (hi > T_DIM) hi = T_DIM;
    double sig_d = 0.0;
    for (int tt = lo; tt < hi; ++tt) sig_d += (double)smag[tt];
    float sig = (float)sig_d, noise = (float)noise_d;
    float d   = sig - noise;
    float snr = 10.0f * log10f((d * d) / (noise * noise));
    float hbf = 12.5f * (snr - 20.0f) + 27.0f;
    int hb = (int)truncf(hbf);
    if (hb < 8) hb = 8;
    ws->mid[n] = mid;
    ws->hb[n]  = hb;
    int wlo = mid - 8, whi = mid + 8;
    #pragma unroll
    for (int wd = 0; wd < 4; ++wd) {
      int base = wd * 64;
      int a = wlo - base; if (a < 0) a = 0;
      int bq = whi - base; if (bq > 64) bq = 64;
      unsigned long long msk = 0ULL;
      if (bq > a) {
        unsigned long long hiM = (bq >= 64) ? ~0ULL : ((1ULL << bq) - 1ULL);
        unsigned long long loM = (1ULL << a) - 1ULL;
        msk = hiM & ~loM;
      }
      ws->tbits[n][wd] = msk;
    }
  }
}

// ---- K3: union mask per freq row — VERBATIM from round 7 (passed) -----------
__global__ __launch_bounds__(256) void k_mask(WS* __restrict__ ws) {
  int f = blockIdx.x * blockDim.x + threadIdx.x;
  if (f >= F_DIM) return;
  unsigned long long m0 = 0, m1 = 0, m2 = 0, m3 = 0;
  #pragma unroll 4
  for (int n = 0; n < N_S; ++n) {
    int hb = ws->hb[n];
    if (f >= FC_IDX - hb && f < FC_IDX + hb) {
      m0 |= ws->tbits[n][0]; m1 |= ws->tbits[n][1];
      m2 |= ws->tbits[n][2]; m3 |= ws->tbits[n][3];
    }
  }
  ws->mask[f][0] = m0; ws->mask[f][1] = m1;
  ws->mask[f][2] = m2; ws->mask[f][3] = m3;
}

// ---- K4: masked copy (the big write) — VERBATIM from round 7 (passed) -------
__global__ __launch_bounds__(256) void k_out(const float4* __restrict__ xv,
                                             float4* __restrict__ ov,
                                             const WS* __restrict__ ws) {
  const int total4 = TOTAL4;
  for (int idx = blockIdx.x * blockDim.x + threadIdx.x; idx < total4;
       idx += gridDim.x * blockDim.x) {
    int t4   = idx & 63;                // float4 index within the T row
    int rest = idx >> 6;
    int f    = rest % F_DIM;
    unsigned long long word = ws->mask[f][t4 >> 4];
    int bits = (int)(word >> ((t4 & 15) * 4)) & 0xF;
    float4 r = {0.f, 0.f, 0.f, 0.f};
    if (bits) {
      float4 v = xv[idx];
      if (bits & 1) r.x = v.x;
      if (bits & 2) r.y = v.y;
      if (bits & 4) r.z = v.z;
      if (bits & 8) r.w = v.w;
    }
    ov[idx] = r;
  }
}

extern "C" void kernel_launch(void* const* d_in, const int* in_sizes, int n_in,
                              void* d_out, int out_size, void* d_ws, size_t ws_size,
                              hipStream_t stream) {
  const float* x   = (const float*)d_in[0];
  float*       out = (float*)d_out;
  WS*          ws  = (WS*)d_ws;

  dim3 gn(NB, N_S);
  k_noise<<<gn, 256, 0, stream>>>((const f4*)x, ws);
  k_stats<<<N_S, 256, 0, stream>>>(x, ws);
  k_mask <<<(F_DIM + 255) / 256, 256, 0, stream>>>(ws);
  k_out  <<<8192, 256, 0, stream>>>((const float4*)x, (float4*)out, ws);
}